// Round 7
// baseline (647.184 us; speedup 1.0000x reference)
//
#include <hip/hip_runtime.h>

#define DT 0.1f
#define NSTEPS 10

#if __has_builtin(__builtin_amdgcn_exp2f)
#define EXP2(x) __builtin_amdgcn_exp2f(x)
#else
#define EXP2(x) exp2f(x)
#endif

#if __has_builtin(__builtin_amdgcn_rcpf)
#define RCP(x) __builtin_amdgcn_rcpf(x)
#else
#define RCP(x) (1.0f / (x))
#endif

#if __has_builtin(__builtin_amdgcn_sqrtf)
#define SQRTF(x) __builtin_amdgcn_sqrtf(x)
#else
#define SQRTF(x) sqrtf(x)
#endif

// tanh over 4 independent scalars with ONE hardware rcp.
// tanh(x) = 2/(e^{-2x}+1) - 1 ; e^{-2x} = exp2(-2*log2e * x).
// Clamp keeps every q in [1, 1+2^28.9]: product finite, no 0*inf.
static __device__ __forceinline__ void tanh4(float& a, float& b, float& c, float& d) {
    float xa = fminf(fmaxf(a, -10.0f), 10.0f);
    float xb = fminf(fmaxf(b, -10.0f), 10.0f);
    float xc = fminf(fmaxf(c, -10.0f), 10.0f);
    float xd = fminf(fmaxf(d, -10.0f), 10.0f);
    float qa = EXP2(xa * -2.8853900818f) + 1.0f;
    float qb = EXP2(xb * -2.8853900818f) + 1.0f;
    float qc = EXP2(xc * -2.8853900818f) + 1.0f;
    float qd = EXP2(xd * -2.8853900818f) + 1.0f;
    float qab = qa * qb;
    float qcd = qc * qd;
    float r   = RCP(qab * qcd);
    float rab = r * qcd;   // 1/(qa*qb)
    float rcd = r * qab;   // 1/(qc*qd)
    a = fmaf(rab * qb, 2.0f, -1.0f);
    b = fmaf(rab * qa, 2.0f, -1.0f);
    c = fmaf(rcd * qd, 2.0f, -1.0f);
    d = fmaf(rcd * qc, 2.0f, -1.0f);
}

// tanh-MLP 4->8->8->2 on 4 rows, scalar math.
// Weight scalars are loaded once per neuron and reused across the 4 rows;
// every VALU op reads at most one uniform operand (mul/fma/add forms).
static __device__ __forceinline__ void policy4(
    const float* __restrict__ w1, const float* __restrict__ b1,
    const float* __restrict__ w2, const float* __restrict__ b2,
    const float* __restrict__ w3, const float* __restrict__ b3,
    const float c0[4], const float c1[4], const float c2[4], const float c3[4],
    float o0[4], float o1[4])
{
    float h[4][8];
#pragma unroll
    for (int j = 0; j < 8; ++j) {
        float wj0 = w1[j * 4 + 0];
        float wj1 = w1[j * 4 + 1];
        float wj2 = w1[j * 4 + 2];
        float wj3 = w1[j * 4 + 3];
        float bj  = b1[j];
#pragma unroll
        for (int r = 0; r < 4; ++r) {
            float z = wj1 * c1[r];          // v_mul: 1 SGPR + VGPR
            z = fmaf(wj0, c0[r], z);
            z = fmaf(wj2, c2[r], z);
            z = fmaf(wj3, c3[r], z);
            z = z + bj;                     // v_add: SGPR + VGPR
            h[r][j] = z;
        }
    }
#pragma unroll
    for (int j = 0; j < 8; ++j) tanh4(h[0][j], h[1][j], h[2][j], h[3][j]);

    float g[4][8];
#pragma unroll
    for (int j = 0; j < 8; ++j) {
        float wk0 = w2[j * 8 + 0];
        float wk1 = w2[j * 8 + 1];
        float wk2 = w2[j * 8 + 2];
        float wk3 = w2[j * 8 + 3];
        float wk4 = w2[j * 8 + 4];
        float wk5 = w2[j * 8 + 5];
        float wk6 = w2[j * 8 + 6];
        float wk7 = w2[j * 8 + 7];
        float bj  = b2[j];
#pragma unroll
        for (int r = 0; r < 4; ++r) {
            float z = wk0 * h[r][0];
            z = fmaf(wk1, h[r][1], z);
            z = fmaf(wk2, h[r][2], z);
            z = fmaf(wk3, h[r][3], z);
            z = fmaf(wk4, h[r][4], z);
            z = fmaf(wk5, h[r][5], z);
            z = fmaf(wk6, h[r][6], z);
            z = fmaf(wk7, h[r][7], z);
            z = z + bj;
            g[r][j] = z;
        }
    }
#pragma unroll
    for (int j = 0; j < 8; ++j) tanh4(g[0][j], g[1][j], g[2][j], g[3][j]);

    {
        float u0 = w3[0], u1 = w3[1], u2 = w3[2], u3 = w3[3];
        float u4 = w3[4], u5 = w3[5], u6 = w3[6], u7 = w3[7];
        float v0 = w3[8], v1 = w3[9], v2 = w3[10], v3 = w3[11];
        float v4 = w3[12], v5 = w3[13], v6 = w3[14], v7 = w3[15];
        float e0 = b3[0], e1 = b3[1];
#pragma unroll
        for (int r = 0; r < 4; ++r) {
            float z = u0 * g[r][0];
            z = fmaf(u1, g[r][1], z);
            z = fmaf(u2, g[r][2], z);
            z = fmaf(u3, g[r][3], z);
            z = fmaf(u4, g[r][4], z);
            z = fmaf(u5, g[r][5], z);
            z = fmaf(u6, g[r][6], z);
            z = fmaf(u7, g[r][7], z);
            o0[r] = z + e0;
            float y = v0 * g[r][0];
            y = fmaf(v1, g[r][1], y);
            y = fmaf(v2, g[r][2], y);
            y = fmaf(v3, g[r][3], y);
            y = fmaf(v4, g[r][4], y);
            y = fmaf(v5, g[r][5], y);
            y = fmaf(v6, g[r][6], y);
            y = fmaf(v7, g[r][7], y);
            o1[r] = y + e1;
        }
    }
}

__global__ void __launch_bounds__(256) rollout_kernel(
    const float* __restrict__ s_star, const float* __restrict__ s0,
    const float* __restrict__ fc1_w, const float* __restrict__ fc1_b,
    const float* __restrict__ fc2_w, const float* __restrict__ fc2_b,
    const float* __restrict__ rc1_w, const float* __restrict__ rc1_b,
    const float* __restrict__ rc2_w, const float* __restrict__ rc2_b,
    const float* __restrict__ rc3_w, const float* __restrict__ rc3_b,
    const float* __restrict__ rr1_w, const float* __restrict__ rr1_b,
    const float* __restrict__ rr2_w, const float* __restrict__ rr2_b,
    const float* __restrict__ rr3_w, const float* __restrict__ rr3_b,
    float* __restrict__ out, int NQ)  // NQ = number of row-quads
{
    int i = blockIdx.x * blockDim.x + threadIdx.x;
    if (i >= NQ) return;

    // rows 4i..4i+3
    float4 ssA = reinterpret_cast<const float4*>(s_star)[2 * i];
    float4 ssB = reinterpret_cast<const float4*>(s_star)[2 * i + 1];
    float4 svA = reinterpret_cast<const float4*>(s0)[2 * i];
    float4 svB = reinterpret_cast<const float4*>(s0)[2 * i + 1];

    float ssx[4] = {ssA.x, ssA.z, ssB.x, ssB.z};
    float ssy[4] = {ssA.y, ssA.w, ssB.y, ssB.w};
    float sx[4]  = {svA.x, svA.z, svB.x, svB.z};
    float sy[4]  = {svA.y, svA.w, svB.y, svB.w};

    // Fuse linear predictor ah = fc2(fc1(x)) = A @ [s, s_star] + cb  (uniform A, cb)
    float A[2][4];
    float cb[2];
#pragma unroll
    for (int r = 0; r < 2; ++r) {
#pragma unroll
        for (int c = 0; c < 4; ++c) {
            float a = 0.0f;
#pragma unroll
            for (int j = 0; j < 4; ++j)
                a = fmaf(fc2_w[r * 4 + j], fc1_w[j * 4 + c], a);
            A[r][c] = a;
        }
        float b = fc2_b[r];
#pragma unroll
        for (int j = 0; j < 4; ++j) b = fmaf(fc2_w[r * 4 + j], fc1_b[j], b);
        cb[r] = b;
    }

    float d0[4], d1[4], ahs0[4], err[4];
#pragma unroll
    for (int r = 0; r < 4; ++r) {
        d0[r] = fmaf(A[0][2], ssx[r], fmaf(A[0][3], ssy[r], cb[0]));
        d1[r] = fmaf(A[1][2], ssx[r], fmaf(A[1][3], ssy[r], cb[1]));
        ahs0[r] = (ssx[r] > 0.5f) ? -1.0f : 1.0f;
        err[r] = 0.0f;
    }

#pragma unroll 1
    for (int t = 0; t < NSTEPS; ++t) {
        float ah0[4], ah1[4], arr0[4], arr1[4], ar0[4], ar1[4];
#pragma unroll
        for (int r = 0; r < 4; ++r) {
            ah0[r] = fmaf(A[0][0], sx[r], fmaf(A[0][1], sy[r], d0[r]));
            ah1[r] = fmaf(A[1][0], sx[r], fmaf(A[1][1], sy[r], d1[r]));
        }
        policy4(rr1_w, rr1_b, rr2_w, rr2_b, rr3_w, rr3_b,
                sx, sy, ah0, ah1, arr0, arr1);
        policy4(rc1_w, rc1_b, rc2_w, rc2_b, rc3_w, rc3_b,
                sx, sy, ah0, ah1, ar0, ar1);

#pragma unroll
        for (int r = 0; r < 4; ++r) {
            sx[r] = fmaf(DT, ar0[r], sx[r]);
            sy[r] = fmaf(DT, ar1[r], sy[r]);

            float dx = ssx[r] - sx[r], dy = ssy[r] - sy[r];
            float n1 = fmaf(dx, dx, dy * dy);
            float ux = arr0[r] - ar0[r], uy = arr1[r] - ar1[r];
            float n2 = fmaf(ux, ux, uy * uy);
            float vx = ahs0[r] - ah0[r];
            float n3 = fmaf(vx, vx, ah1[r] * ah1[r]);

            err[r] = err[r] + SQRTF(n1);
            err[r] = fmaf(0.1f, SQRTF(n2), err[r]);
            err[r] = err[r] + SQRTF(n3);
        }
    }

    float4 o;
    o.x = err[0]; o.y = err[1]; o.z = err[2]; o.w = err[3];
    reinterpret_cast<float4*>(out)[i] = o;
}

extern "C" void kernel_launch(void* const* d_in, const int* in_sizes, int n_in,
                              void* d_out, int out_size, void* d_ws, size_t ws_size,
                              hipStream_t stream) {
    const float* s_star = (const float*)d_in[0];
    const float* s0     = (const float*)d_in[1];
    const float* fc1_w  = (const float*)d_in[2];
    const float* fc1_b  = (const float*)d_in[3];
    const float* fc2_w  = (const float*)d_in[4];
    const float* fc2_b  = (const float*)d_in[5];
    const float* rc1_w  = (const float*)d_in[6];
    const float* rc1_b  = (const float*)d_in[7];
    const float* rc2_w  = (const float*)d_in[8];
    const float* rc2_b  = (const float*)d_in[9];
    const float* rc3_w  = (const float*)d_in[10];
    const float* rc3_b  = (const float*)d_in[11];
    const float* rr1_w  = (const float*)d_in[12];
    const float* rr1_b  = (const float*)d_in[13];
    const float* rr2_w  = (const float*)d_in[14];
    const float* rr2_b  = (const float*)d_in[15];
    const float* rr3_w  = (const float*)d_in[16];
    const float* rr3_b  = (const float*)d_in[17];
    float* out = (float*)d_out;

    int B = in_sizes[0] / 2;   // rows
    int NQ = B / 4;            // row-quads (B = 4194304)
    int block = 256;
    int grid = (NQ + block - 1) / block;
    rollout_kernel<<<grid, block, 0, stream>>>(
        s_star, s0, fc1_w, fc1_b, fc2_w, fc2_b,
        rc1_w, rc1_b, rc2_w, rc2_b, rc3_w, rc3_b,
        rr1_w, rr1_b, rr2_w, rr2_b, rr3_w, rr3_b,
        out, NQ);
}